// Round 19
// baseline (1796.990 us; speedup 1.0000x reference)
//
#include <hip/hip_runtime.h>
#include <math.h>

#define HH  64
#define TT  2048
#define IND 7
#define NT  128          // 2 waves: wave0 = layer0, wave1 = layer1 (decoupled)
#define RING 32

typedef _Float16 half_t;
typedef _Float16 h2v __attribute__((ext_vector_type(2)));
typedef _Float16 h8v __attribute__((ext_vector_type(8)));

#define LOG2E 1.44269504088896f

// constant-index h2v slice of an h8v: exact VGPR subregister
#define S2C(V, I) __builtin_shufflevector(V, V, 2*(I), 2*(I)+1)

// f16 dot2 with fp32 accumulate
__device__ __forceinline__ float fdot2(h2v a, h2v b, float c) {
#if __has_builtin(__builtin_amdgcn_fdot2)
    return __builtin_amdgcn_fdot2(a, b, c, false);
#else
    return fmaf((float)a.x, (float)b.x, fmaf((float)a.y, (float)b.y, c));
#endif
}

__device__ __forceinline__ float exp2_fast(float x) {
#if __has_builtin(__builtin_amdgcn_exp2f)
    return __builtin_amdgcn_exp2f(x);
#else
    return exp2f(x);
#endif
}
__device__ __forceinline__ float rcp_fast(float x) {
#if __has_builtin(__builtin_amdgcn_rcpf)
    return __builtin_amdgcn_rcpf(x);
#else
    return __fdividef(1.0f, x);
#endif
}

// sigmoid / tanh with log2e-pre-scaled arguments (verified r13-r18)
__device__ __forceinline__ float sig2(float ahat) {
    return rcp_fast(1.0f + exp2_fast(-ahat));
}
__device__ __forceinline__ float tanh2(float c) {
    float e = exp2_fast(c * (-2.0f * LOG2E));
    return fmaf(2.0f, rcp_fast(1.0f + e), -1.0f);
}

// 4 f16-dot2 of weight block (W)[0..3] against the 4 h2v slices of h8v H
#define DOT4(ACC, W, H) \
    ACC = fdot2((W)[0], S2C(H, 0), ACC); \
    ACC = fdot2((W)[1], S2C(H, 1), ACC); \
    ACC = fdot2((W)[2], S2C(H, 2), ACC); \
    ACC = fdot2((W)[3], S2C(H, 3), ACC);

__global__ __launch_bounds__(NT) __attribute__((amdgpu_waves_per_eu(1, 1)))
void lstm2_fused(
    const float* __restrict__ x,     // (B,7,2048)
    const float* __restrict__ Wih0,  // (256,7)
    const float* __restrict__ Whh0,  // (256,64)
    const float* __restrict__ bih0, const float* __restrict__ bhh0,
    const float* __restrict__ Wih1,  // (256,64)
    const float* __restrict__ Whh1,  // (256,64)
    const float* __restrict__ bih1, const float* __restrict__ bhh1,
    const float* __restrict__ W1,    // (10,64)
    const float* __restrict__ b1v,   // (10)
    const float* __restrict__ gmma, const float* __restrict__ beta,
    const float* __restrict__ rm,   const float* __restrict__ rv,
    const float* __restrict__ W2,   // (1,10)
    const float* __restrict__ b2,   // (1)
    float* __restrict__ out)         // (B,1)
{
    const int b    = blockIdx.x;
    const int tid  = threadIdx.x;
    const int wave = tid >> 6;       // 0: layer0   1: layer1
    const int lane = tid & 63;       // lane = hidden unit j

    __shared__ __align__(16) half_t xTh[TT][8];        // 32 KB f16 x, [7]=0 pad
    __shared__ __align__(16) half_t h0ring[RING][HH];  // 4 KB h0 ring
    __shared__ __align__(16) half_t h1ring[2][HH];     // h1 double buffer (wave1-private)
    __shared__ int progs[2];                           // [0]=L0 produced, [1]=L1 consumed
    __shared__ float yv[10];

    // ---- stage x[b] transposed, converted to f16; init rings/flags ----
    {
        const float* xg = x + (size_t)b * (IND * TT);
        for (int i = tid; i < IND * TT; i += NT) {
            int d = i >> 11;
            int t = i & (TT - 1);
            xTh[t][d] = (half_t)xg[i];
        }
        for (int t = tid; t < TT; t += NT) xTh[t][7] = (half_t)0.0f;
        if (tid < HH) {
            h0ring[RING - 1][tid] = (half_t)0.0f;   // h0(-1)
            h1ring[1][tid]        = (half_t)0.0f;   // h1(-1)
        }
        if (tid == 0) { progs[0] = 0; progs[1] = 0; }
    }
    __syncthreads();

    if (wave == 0) {
        // ========== LAYER-0 wave: lane=unit, 4 gates, full k in-lane ==========
        h2v wh[4][32];   // Whh0 full rows, 4 gates
        h2v xw[4][4];    // Wih0 rows ([7]=0)
        float bg[4];
        #pragma unroll
        for (int s = 0; s < 4; ++s) {
            const int g = (s << 6) | lane;
            const float sc = (s == 2) ? 2.0f * LOG2E : LOG2E;
            const float* pw = Whh0 + g * HH;
            #pragma unroll
            for (int r = 0; r < 32; ++r)
                wh[s][r] = h2v{(half_t)(pw[2*r] * sc), (half_t)(pw[2*r+1] * sc)};
            float t8[8];
            #pragma unroll
            for (int d = 0; d < 8; ++d)
                t8[d] = (d < IND) ? Wih0[g * IND + d] * sc : 0.0f;
            #pragma unroll
            for (int r = 0; r < 4; ++r)
                xw[s][r] = h2v{(half_t)t8[2*r], (half_t)t8[2*r+1]};
            bg[s] = (bih0[g] + bhh0[g]) * sc;
        }

        float c0 = 0.0f;
        for (int t = 0; t < TT; ++t) {
            // backpressure: slot t&31 must be consumed (prog1 >= t-31)
            if (t >= RING) {
                while (*(volatile int*)&progs[1] < t - (RING - 1)) { }
            }
            const h8v* hp = (const h8v*)&h0ring[(t - 1) & (RING - 1)][0];
            h8v H0 = hp[0], H1 = hp[1], H2 = hp[2], H3 = hp[3];
            h8v H4 = hp[4], H5 = hp[5], H6 = hp[6], H7 = hp[7];
            h8v XV = *((const h8v*)&xTh[t][0]);
            float fr[4];
            #pragma unroll
            for (int s = 0; s < 4; ++s) {
                float a0 = bg[s], a1 = 0.f, a2 = 0.f, a3 = 0.f;
                DOT4(a0, &wh[s][0],  H0)
                DOT4(a1, &wh[s][4],  H1)
                DOT4(a2, &wh[s][8],  H2)
                DOT4(a3, &wh[s][12], H3)
                DOT4(a0, &wh[s][16], H4)
                DOT4(a1, &wh[s][20], H5)
                DOT4(a2, &wh[s][24], H6)
                DOT4(a3, &wh[s][28], H7)
                DOT4(a0, &xw[s][0],  XV)
                fr[s] = (a0 + a1) + (a2 + a3);
            }
            float iv = sig2(fr[0]);
            float fv = sig2(fr[1]);
            float gv = fmaf(2.0f, sig2(fr[2]), -1.0f);
            float ov = sig2(fr[3]);
            c0 = fmaf(fv, c0, iv * gv);
            float hn = ov * tanh2(c0);
            h0ring[t & (RING - 1)][lane] = (half_t)hn;
            __threadfence_block();                       // drain data write
            if (lane == 0) *(volatile int*)&progs[0] = t + 1;
        }
    } else {
        // ========== LAYER-1 wave: lane=unit, 4 gates, full k in-lane ==========
        h2v wi[4][32], wr[4][32];   // Wih1, Whh1 full rows (256 f16 VGPRs)
        float bg[4];
        #pragma unroll
        for (int s = 0; s < 4; ++s) {
            const int g = (s << 6) | lane;
            const float sc = (s == 2) ? 2.0f * LOG2E : LOG2E;
            const float* p0 = Wih1 + g * HH;
            const float* p1 = Whh1 + g * HH;
            #pragma unroll
            for (int r = 0; r < 32; ++r) {
                wi[s][r] = h2v{(half_t)(p0[2*r] * sc), (half_t)(p0[2*r+1] * sc)};
                wr[s][r] = h2v{(half_t)(p1[2*r] * sc), (half_t)(p1[2*r+1] * sc)};
            }
            bg[s] = (bih1[g] + bhh1[g]) * sc;
        }

        float c1 = 0.0f;
        for (int t = 0; t < TT; ++t) {
            // wait for h0(t)
            while (*(volatile int*)&progs[0] < t + 1) { }
            const h8v* hp = (const h8v*)&h0ring[t & (RING - 1)][0];
            h8v H0 = hp[0], H1 = hp[1], H2 = hp[2], H3 = hp[3];
            h8v H4 = hp[4], H5 = hp[5], H6 = hp[6], H7 = hp[7];
            const h8v* gq = (const h8v*)&h1ring[(t - 1) & 1][0];
            h8v G0 = gq[0], G1 = gq[1], G2 = gq[2], G3 = gq[3];
            h8v G4 = gq[4], G5 = gq[5], G6 = gq[6], G7 = gq[7];
            __threadfence_block();                       // loads complete
            if (lane == 0) *(volatile int*)&progs[1] = t + 1;   // slot consumed
            float fr[4];
            #pragma unroll
            for (int s = 0; s < 4; ++s) {
                float a0 = bg[s], a1 = 0.f, a2 = 0.f, a3 = 0.f;
                DOT4(a0, &wi[s][0],  H0)
                DOT4(a1, &wi[s][4],  H1)
                DOT4(a2, &wi[s][8],  H2)
                DOT4(a3, &wi[s][12], H3)
                DOT4(a0, &wi[s][16], H4)
                DOT4(a1, &wi[s][20], H5)
                DOT4(a2, &wi[s][24], H6)
                DOT4(a3, &wi[s][28], H7)
                DOT4(a0, &wr[s][0],  G0)
                DOT4(a1, &wr[s][4],  G1)
                DOT4(a2, &wr[s][8],  G2)
                DOT4(a3, &wr[s][12], G3)
                DOT4(a0, &wr[s][16], G4)
                DOT4(a1, &wr[s][20], G5)
                DOT4(a2, &wr[s][24], G6)
                DOT4(a3, &wr[s][28], G7)
                fr[s] = (a0 + a1) + (a2 + a3);
            }
            float iv = sig2(fr[0]);
            float fv = sig2(fr[1]);
            float gv = fmaf(2.0f, sig2(fr[2]), -1.0f);
            float ov = sig2(fr[3]);
            c1 = fmaf(fv, c1, iv * gv);
            float hn = ov * tanh2(c1);
            h1ring[t & 1][lane] = (half_t)hn;            // wave-private, in-order DS
        }
    }

    __syncthreads();

    // ---- head: y = relu(bn(h1(TT-1) @ W1^T + b1)) @ W2^T + b2 ----
    if (tid < 10) {
        float y = b1v[tid];
        #pragma unroll
        for (int k = 0; k < HH; ++k) y += W1[tid * HH + k] * (float)h1ring[1][k];
        y = (y - rm[tid]) * rsqrtf(rv[tid] + 1e-5f) * gmma[tid] + beta[tid];
        y = fmaxf(y, 0.0f);
        yv[tid] = y * W2[tid];
    }
    __syncthreads();
    if (tid == 0) {
        float sacc = b2[0];
        #pragma unroll
        for (int k = 0; k < 10; ++k) sacc += yv[k];
        out[b] = sacc;
    }
}

extern "C" void kernel_launch(void* const* d_in, const int* in_sizes, int n_in,
                              void* d_out, int out_size, void* d_ws, size_t ws_size,
                              hipStream_t stream) {
    const float* x    = (const float*)d_in[0];
    const float* Wih0 = (const float*)d_in[1];
    const float* Whh0 = (const float*)d_in[2];
    const float* bih0 = (const float*)d_in[3];
    const float* bhh0 = (const float*)d_in[4];
    const float* Wih1 = (const float*)d_in[5];
    const float* Whh1 = (const float*)d_in[6];
    const float* bih1 = (const float*)d_in[7];
    const float* bhh1 = (const float*)d_in[8];
    const float* W1   = (const float*)d_in[9];
    const float* b1   = (const float*)d_in[10];
    const float* gmma = (const float*)d_in[11];
    const float* beta = (const float*)d_in[12];
    const float* rm   = (const float*)d_in[13];
    const float* rv   = (const float*)d_in[14];
    const float* W2   = (const float*)d_in[15];
    const float* b2   = (const float*)d_in[16];

    const int B = in_sizes[0] / (IND * TT);   // 256

    lstm2_fused<<<dim3(B), dim3(NT), 0, stream>>>(
        x, Wih0, Whh0, bih0, bhh0, Wih1, Whh1, bih1, bhh1,
        W1, b1, gmma, beta, rm, rv, W2, b2, (float*)d_out);
}

// Round 20
// 1208.007 us; speedup vs baseline: 1.4876x; 1.4876x over previous
//
#include <hip/hip_runtime.h>
#include <math.h>

#define HH  64
#define TT  2048
#define IND 7
#define NT  256          // 4 waves: 0,1 = L0(+z)   2,3 = L1(+xp)

typedef _Float16 half_t;
typedef _Float16 h2v __attribute__((ext_vector_type(2)));
typedef _Float16 h8v __attribute__((ext_vector_type(8)));
typedef float    f4v __attribute__((ext_vector_type(4)));
typedef unsigned int u2v __attribute__((ext_vector_type(2)));

#define LOG2E 1.44269504088896f

// constant-index h2v slice of an h8v: exact VGPR subregister
#define S2C(V, I) __builtin_shufflevector(V, V, 2*(I), 2*(I)+1)

// f16 dot2 with fp32 accumulate
__device__ __forceinline__ float fdot2(h2v a, h2v b, float c) {
#if __has_builtin(__builtin_amdgcn_fdot2)
    return __builtin_amdgcn_fdot2(a, b, c, false);
#else
    return fmaf((float)a.x, (float)b.x, fmaf((float)a.y, (float)b.y, c));
#endif
}

__device__ __forceinline__ float exp2_fast(float x) {
#if __has_builtin(__builtin_amdgcn_exp2f)
    return __builtin_amdgcn_exp2f(x);
#else
    return exp2f(x);
#endif
}
__device__ __forceinline__ float rcp_fast(float x) {
#if __has_builtin(__builtin_amdgcn_rcpf)
    return __builtin_amdgcn_rcpf(x);
#else
    return __fdividef(1.0f, x);
#endif
}

// value held by the lane^32 partner (VALU pipe, v_permlane32_swap; verified r9-r19)
__device__ __forceinline__ float partner32(float x, int kh) {
#if __has_builtin(__builtin_amdgcn_permlane32_swap)
    u2v r = __builtin_amdgcn_permlane32_swap(__float_as_uint(x), __float_as_uint(x), false, false);
    return kh ? __uint_as_float(r.x) : __uint_as_float(r.y);
#else
    return __shfl_xor(x, 32);
#endif
}

// sigmoid / tanh with log2e-pre-scaled arguments (verified r13-r19)
__device__ __forceinline__ float sig2(float ahat) {
    return rcp_fast(1.0f + exp2_fast(-ahat));
}
__device__ __forceinline__ float tanh2(float c) {
    float e = exp2_fast(c * (-2.0f * LOG2E));
    return fmaf(2.0f, rcp_fast(1.0f + e), -1.0f);
}

// 4 f16-dot2 of weight block (W)[0..3] against the 4 h2v slices of h8v H
#define DOT4(ACC, W, H) \
    ACC = fdot2((W)[0], S2C(H, 0), ACC); \
    ACC = fdot2((W)[1], S2C(H, 1), ACC); \
    ACC = fdot2((W)[2], S2C(H, 2), ACC); \
    ACC = fdot2((W)[3], S2C(H, 3), ACC);

__global__ __launch_bounds__(NT) __attribute__((amdgpu_waves_per_eu(1, 1)))
void lstm2_fused(
    const float* __restrict__ x,     // (B,7,2048)
    const float* __restrict__ Wih0,  // (256,7)
    const float* __restrict__ Whh0,  // (256,64)
    const float* __restrict__ bih0, const float* __restrict__ bhh0,
    const float* __restrict__ Wih1,  // (256,64)
    const float* __restrict__ Whh1,  // (256,64)
    const float* __restrict__ bih1, const float* __restrict__ bhh1,
    const float* __restrict__ W1,    // (10,64)
    const float* __restrict__ b1v,   // (10)
    const float* __restrict__ gmma, const float* __restrict__ beta,
    const float* __restrict__ rm,   const float* __restrict__ rv,
    const float* __restrict__ W2,   // (1,10)
    const float* __restrict__ b2,   // (1)
    float* __restrict__ out)         // (B,1)
{
    const int b    = blockIdx.x;
    const int tid  = threadIdx.x;
    const int wave = tid >> 6;       // 0,1: L0   2,3: L1
    const int lane = tid & 63;
    const int kh   = lane >> 5;                        // k-half (lane bit 5)
    const int j    = ((wave & 1) << 5) | (lane & 31);  // hidden unit 0..63
    const bool pub = (kh == 0);

    __shared__ __align__(16) half_t xTh[TT][8];      // 32 KB f16 x, [7]=0 pad
    __shared__ __align__(16) half_t h0r[2][HH];      // h0 double buffer
    __shared__ __align__(16) half_t h1r[2][HH];      // h1 double buffer
    __shared__ __align__(16) float  zr[2][2][HH][4]; // z1 partials [slot][kh][unit][gate]
    __shared__ __align__(16) float  xr[2][HH][4];    // xproj0 (bias folded) [slot][unit][gate]
    __shared__ float yv[10];

    // ---- stage x[b] transposed, f16; init rings; bootstrap xp(0) ----
    {
        const float* xg = x + (size_t)b * (IND * TT);
        for (int i = tid; i < IND * TT; i += NT) {
            int d = i >> 11;
            int t = i & (TT - 1);
            xTh[t][d] = (half_t)xg[i];
        }
        for (int t = tid; t < TT; t += NT) xTh[t][7] = (half_t)0.0f;
        if (tid < HH) {
            h0r[1][tid] = (half_t)0.0f;   // h0(-1)
            h1r[1][tid] = (half_t)0.0f;   // h1(-1)
            #pragma unroll
            for (int s = 0; s < 4; ++s) {
                const int g = (s << 6) | tid;
                const float sc = (s == 2) ? 2.0f * LOG2E : LOG2E;
                float acc = bih0[g] + bhh0[g];
                #pragma unroll
                for (int d = 0; d < IND; ++d) acc += Wih0[g * IND + d] * xg[d * TT];
                xr[0][tid][s] = acc * sc;   // xp(0)
            }
        }
    }
    __syncthreads();

    if (wave < 2) {
        // ====== L0 waves: h0(T) at tick T; also z1(T-1)=Wih1@h0(T-1) partials ======
        h2v wh[4][16], wz[4][16];   // Whh0 / Wih1 k-half rows, 4 gates (128 VGPR)
        #pragma unroll
        for (int s = 0; s < 4; ++s) {
            const int g = (s << 6) | j;
            const float sc = (s == 2) ? 2.0f * LOG2E : LOG2E;
            const float* pw = Whh0 + g * HH + 32 * kh;
            const float* pz = Wih1 + g * HH + 32 * kh;
            #pragma unroll
            for (int r = 0; r < 16; ++r) {
                wh[s][r] = h2v{(half_t)(pw[2*r] * sc), (half_t)(pw[2*r+1] * sc)};
                wz[s][r] = h2v{(half_t)(pz[2*r] * sc), (half_t)(pz[2*r+1] * sc)};
            }
        }
        float c0 = 0.0f;

        for (int T = 0; T <= TT + 1; ++T) {
            if (T <= TT) {
                const h8v* hp = (const h8v*)&h0r[(T - 1) & 1][32 * kh];
                h8v H0 = hp[0], H1 = hp[1], H2 = hp[2], H3 = hp[3];
                if (T < TT) {
                    f4v xp = *((const f4v*)&xr[T & 1][j][0]);   // Wih0@x(T)+b0, full
                    float fr[4];
                    #pragma unroll
                    for (int s = 0; s < 4; ++s) {
                        // xp counted once: only pub lanes' acc enters combine un-doubled
                        float a0 = pub ? xp[s] : 0.0f;
                        float a1 = 0.f, a2 = 0.f, a3 = 0.f;
                        DOT4(a0, &wh[s][0],  H0)
                        DOT4(a1, &wh[s][4],  H1)
                        DOT4(a2, &wh[s][8],  H2)
                        DOT4(a3, &wh[s][12], H3)
                        fr[s] = (a0 + a1) + (a2 + a3);
                    }
                    float fi = fr[0] + partner32(fr[0], kh);
                    float ff = fr[1] + partner32(fr[1], kh);
                    float fg = fr[2] + partner32(fr[2], kh);
                    float fo = fr[3] + partner32(fr[3], kh);
                    float iv = sig2(fi);
                    float fv = sig2(ff);
                    float gv = fmaf(2.0f, sig2(fg), -1.0f);
                    float ov = sig2(fo);
                    c0 = fmaf(fv, c0, iv * gv);
                    float hn = ov * tanh2(c0);
                    if (pub) h0r[T & 1][j] = (half_t)hn;
                }
                if (T >= 1) {
                    // z1(T-1) partials from the SAME H registers (no extra LDS reads)
                    float za[4];
                    #pragma unroll
                    for (int s = 0; s < 4; ++s) {
                        float a0 = 0.f, a1 = 0.f, a2 = 0.f, a3 = 0.f;
                        DOT4(a0, &wz[s][0],  H0)
                        DOT4(a1, &wz[s][4],  H1)
                        DOT4(a2, &wz[s][8],  H2)
                        DOT4(a3, &wz[s][12], H3)
                        za[s] = (a0 + a1) + (a2 + a3);
                    }
                    *((f4v*)&zr[(T - 1) & 1][kh][j][0]) = f4v{za[0], za[1], za[2], za[3]};
                }
            }
            __syncthreads();
        }
    } else {
        // ====== L1 waves: h1(T-2) at tick T (lag 2); also xp0(T+1) producer ======
        h2v wr[4][16], wx[4][4];    // Whh1 k-half + Wih0 rows (80 VGPR)
        float bg1[4], bx0[4];
        #pragma unroll
        for (int s = 0; s < 4; ++s) {
            const int g = (s << 6) | j;
            const float sc = (s == 2) ? 2.0f * LOG2E : LOG2E;
            const float* pw = Whh1 + g * HH + 32 * kh;
            #pragma unroll
            for (int r = 0; r < 16; ++r)
                wr[s][r] = h2v{(half_t)(pw[2*r] * sc), (half_t)(pw[2*r+1] * sc)};
            float t8[8];
            #pragma unroll
            for (int d = 0; d < 8; ++d)
                t8[d] = (d < IND) ? Wih0[g * IND + d] * sc : 0.0f;
            #pragma unroll
            for (int r = 0; r < 4; ++r)
                wx[s][r] = h2v{(half_t)t8[2*r], (half_t)t8[2*r+1]};
            bg1[s] = (bih1[g] + bhh1[g]) * sc;
            bx0[s] = (bih0[g] + bhh0[g]) * sc;
        }
        float c1 = 0.0f;

        for (int T = 0; T <= TT + 1; ++T) {
            if (T >= 2) {
                const h8v* hq = (const h8v*)&h1r[(T - 3) & 1][32 * kh];
                h8v Q0 = hq[0], Q1 = hq[1], Q2 = hq[2], Q3 = hq[3];
                f4v za = *((const f4v*)&zr[(T - 2) & 1][0][j][0]);
                f4v zb = *((const f4v*)&zr[(T - 2) & 1][1][j][0]);
                f4v zs = za + zb;                    // full Wih1@h0(T-2)
                float fr[4];
                #pragma unroll
                for (int s = 0; s < 4; ++s) {
                    // bias+z counted once (pub lanes only) before the combine
                    float a0 = pub ? (bg1[s] + zs[s]) : 0.0f;
                    float a1 = 0.f, a2 = 0.f, a3 = 0.f;
                    DOT4(a0, &wr[s][0],  Q0)
                    DOT4(a1, &wr[s][4],  Q1)
                    DOT4(a2, &wr[s][8],  Q2)
                    DOT4(a3, &wr[s][12], Q3)
                    fr[s] = (a0 + a1) + (a2 + a3);
                }
                float fi = fr[0] + partner32(fr[0], kh);
                float ff = fr[1] + partner32(fr[1], kh);
                float fg = fr[2] + partner32(fr[2], kh);
                float fo = fr[3] + partner32(fr[3], kh);
                float iv = sig2(fi);
                float fv = sig2(ff);
                float gv = fmaf(2.0f, sig2(fg), -1.0f);
                float ov = sig2(fo);
                c1 = fmaf(fv, c1, iv * gv);
                float hn = ov * tanh2(c1);
                if (pub) h1r[(T - 2) & 1][j] = (half_t)hn;
            }
            if (T + 1 < TT) {
                // produce xp0(T+1) = Wih0@x(T+1) + b0 (full, every lane; pub writes)
                h8v XV = *((const h8v*)&xTh[T + 1][0]);
                float xp[4];
                #pragma unroll
                for (int s = 0; s < 4; ++s) {
                    float a = bx0[s];
                    DOT4(a, &wx[s][0], XV)
                    xp[s] = a;
                }
                if (pub) *((f4v*)&xr[(T + 1) & 1][j][0]) = f4v{xp[0], xp[1], xp[2], xp[3]};
            }
            __syncthreads();
        }
    }

    // h1(TT-1) was published at tick TT+1 into h1r[(TT-1)&1] = h1r[1]
    if (tid < 10) {
        float y = b1v[tid];
        #pragma unroll
        for (int k = 0; k < HH; ++k) y += W1[tid * HH + k] * (float)h1r[1][k];
        y = (y - rm[tid]) * rsqrtf(rv[tid] + 1e-5f) * gmma[tid] + beta[tid];
        y = fmaxf(y, 0.0f);
        yv[tid] = y * W2[tid];
    }
    __syncthreads();
    if (tid == 0) {
        float sacc = b2[0];
        #pragma unroll
        for (int k = 0; k < 10; ++k) sacc += yv[k];
        out[b] = sacc;
    }
}

extern "C" void kernel_launch(void* const* d_in, const int* in_sizes, int n_in,
                              void* d_out, int out_size, void* d_ws, size_t ws_size,
                              hipStream_t stream) {
    const float* x    = (const float*)d_in[0];
    const float* Wih0 = (const float*)d_in[1];
    const float* Whh0 = (const float*)d_in[2];
    const float* bih0 = (const float*)d_in[3];
    const float* bhh0 = (const float*)d_in[4];
    const float* Wih1 = (const float*)d_in[5];
    const float* Whh1 = (const float*)d_in[6];
    const float* bih1 = (const float*)d_in[7];
    const float* bhh1 = (const float*)d_in[8];
    const float* W1   = (const float*)d_in[9];
    const float* b1   = (const float*)d_in[10];
    const float* gmma = (const float*)d_in[11];
    const float* beta = (const float*)d_in[12];
    const float* rm   = (const float*)d_in[13];
    const float* rv   = (const float*)d_in[14];
    const float* W2   = (const float*)d_in[15];
    const float* b2   = (const float*)d_in[16];

    const int B = in_sizes[0] / (IND * TT);   // 256

    lstm2_fused<<<dim3(B), dim3(NT), 0, stream>>>(
        x, Wih0, Whh0, bih0, bhh0, Wih1, Whh1, bih1, bhh1,
        W1, b1, gmma, beta, rm, rv, W2, b2, (float*)d_out);
}

// Round 21
// 997.487 us; speedup vs baseline: 1.8015x; 1.2111x over previous
//
#include <hip/hip_runtime.h>
#include <math.h>

#define HH  64
#define TT  2048
#define IND 7
#define NT  256          // 4 waves: 2 L0 + 2 L1, one per SIMD

typedef _Float16 half_t;
typedef _Float16 h2v __attribute__((ext_vector_type(2)));
typedef _Float16 h8v __attribute__((ext_vector_type(8)));
typedef unsigned int u2v __attribute__((ext_vector_type(2)));

#define LOG2E 1.44269504088896f

// constant-index h2v slice of an h8v: exact VGPR subregister
#define S2C(V, I) __builtin_shufflevector(V, V, 2*(I), 2*(I)+1)

// f16 dot2 with fp32 accumulate
__device__ __forceinline__ float fdot2(h2v a, h2v b, float c) {
#if __has_builtin(__builtin_amdgcn_fdot2)
    return __builtin_amdgcn_fdot2(a, b, c, false);
#else
    return fmaf((float)a.x, (float)b.x, fmaf((float)a.y, (float)b.y, c));
#endif
}

__device__ __forceinline__ float exp2_fast(float x) {
#if __has_builtin(__builtin_amdgcn_exp2f)
    return __builtin_amdgcn_exp2f(x);
#else
    return exp2f(x);
#endif
}
__device__ __forceinline__ float rcp_fast(float x) {
#if __has_builtin(__builtin_amdgcn_rcpf)
    return __builtin_amdgcn_rcpf(x);
#else
    return __fdividef(1.0f, x);
#endif
}

// value held by the lane^32 partner (VALU pipe, v_permlane32_swap; verified r9-r20)
__device__ __forceinline__ float partner32(float x, int hi) {
#if __has_builtin(__builtin_amdgcn_permlane32_swap)
    u2v r = __builtin_amdgcn_permlane32_swap(__float_as_uint(x), __float_as_uint(x), false, false);
    return hi ? __uint_as_float(r.x) : __uint_as_float(r.y);
#else
    return __shfl_xor(x, 32);
#endif
}

// sigmoid with pre-scaled (log2e) argument (verified r13-r20)
__device__ __forceinline__ float sig2(float ahat) {
    return rcp_fast(1.0f + exp2_fast(-ahat));
}
__device__ __forceinline__ float tanh2(float c) {
    float e = exp2_fast(c * (-2.0f * LOG2E));
    return fmaf(2.0f, rcp_fast(1.0f + e), -1.0f);
}

// 4 f16-dot2 of weight block (W)[0..3] against the 4 h2v slices of h8v H
#define DOT4(ACC, W, H) \
    ACC = fdot2((W)[0], S2C(H, 0), ACC); \
    ACC = fdot2((W)[1], S2C(H, 1), ACC); \
    ACC = fdot2((W)[2], S2C(H, 2), ACC); \
    ACC = fdot2((W)[3], S2C(H, 3), ACC);

__global__ __launch_bounds__(NT) __attribute__((amdgpu_waves_per_eu(1, 1)))
void lstm2_fused(
    const float* __restrict__ x,     // (B,7,2048)
    const float* __restrict__ Wih0,  // (256,7)
    const float* __restrict__ Whh0,  // (256,64)
    const float* __restrict__ bih0, const float* __restrict__ bhh0,
    const float* __restrict__ Wih1,  // (256,64)
    const float* __restrict__ Whh1,  // (256,64)
    const float* __restrict__ bih1, const float* __restrict__ bhh1,
    const float* __restrict__ W1,    // (10,64)
    const float* __restrict__ b1v,   // (10)
    const float* __restrict__ gmma, const float* __restrict__ beta,
    const float* __restrict__ rm,   const float* __restrict__ rv,
    const float* __restrict__ W2,   // (1,10)
    const float* __restrict__ b2,   // (1)
    float* __restrict__ out)         // (B,1)
{
    const int b    = blockIdx.x;
    const int tid  = threadIdx.x;
    const int wave = tid >> 6;       // 0,1: L0   2,3: L1
    const int lane = tid & 63;

    __shared__ __align__(16) half_t xTh[TT][8];   // 32 KB, f16 x, [7]=0 pad
    __shared__ __align__(16) half_t h0s[2][HH];   // f16 hidden, double-buffered
    __shared__ __align__(16) half_t h1s[2][HH];
    __shared__ float yv[10];

    // ---- stage x[b] transposed, converted to f16 ----
    {
        const float* xg = x + (size_t)b * (IND * TT);
        for (int i = tid; i < IND * TT; i += NT) {
            int d = i >> 11;
            int t = i & (TT - 1);
            xTh[t][d] = (half_t)xg[i];
        }
        for (int t = tid; t < TT; t += NT) xTh[t][7] = (half_t)0.0f;
        if (tid < HH) {
            h0s[1][tid] = (half_t)0.0f;
            h1s[0][tid] = (half_t)0.0f;
            h1s[1][tid] = (half_t)0.0f;
        }
    }

    __syncthreads();

    if (wave < 2) {
        // ========= LAYER-0 (2 waves): lane = (unit j, k-half kh), 4 gates in-lane =========
        const int j  = ((wave & 1) << 5) | (lane & 31);   // hidden unit 0..63
        const int kh = lane >> 5;                          // k-half (lane bit 5)

        // volatile loads: remat is illegal -> weights stay register-resident
        h2v wh[4][16];    // Whh0 half-rows, 4 gates
        h2v xw[4][4];     // Wih0 rows (kh=1 lanes only; zeros otherwise)
        float bg[4];
        #pragma unroll
        for (int s = 0; s < 4; ++s) {
            const int g = (s << 6) | j;
            const float sc = (s == 2) ? 2.0f * LOG2E : LOG2E;
            const volatile float* pw = Whh0 + g * HH + 32 * kh;
            #pragma unroll
            for (int r = 0; r < 16; ++r) {
                float w0 = pw[2*r], w1 = pw[2*r+1];
                wh[s][r] = h2v{(half_t)(w0 * sc), (half_t)(w1 * sc)};
            }
            const volatile float* px = Wih0 + g * IND;
            float t8[8];
            #pragma unroll
            for (int d = 0; d < IND; ++d) t8[d] = px[d];
            t8[7] = 0.0f;
            #pragma unroll
            for (int d = 0; d < 8; ++d)
                t8[d] = (d < IND && kh) ? t8[d] * sc : 0.0f;
            #pragma unroll
            for (int r = 0; r < 4; ++r)
                xw[s][r] = h2v{(half_t)t8[2*r], (half_t)t8[2*r+1]};
            bg[s] = (kh == 0) ? (bih0[g] + bhh0[g]) * sc : 0.0f;
        }

        float c0 = 0.0f;

        for (int tick = 0; tick <= TT; ++tick) {
            const int p = tick & 1;
            if (tick < TT) {
                const h8v* hp = (const h8v*)&h0s[p ^ 1][32 * kh];
                h8v H0 = hp[0], H1 = hp[1], H2 = hp[2], H3 = hp[3];
                h8v XV = *((const h8v*)&xTh[tick][0]);     // uniform broadcast
                float fa[4], fb[4];
                #pragma unroll
                for (int s = 0; s < 4; ++s) {
                    float a = bg[s], bb = 0.0f;
                    DOT4(a,  &wh[s][0],  H0)
                    DOT4(a,  &wh[s][4],  H1)
                    DOT4(bb, &wh[s][8],  H2)
                    DOT4(bb, &wh[s][12], H3)
                    DOT4(a,  &xw[s][0],  XV)
                    fa[s] = a; fb[s] = bb;
                }
                float fi, ff, fg, fo;
                { float pr = fa[0] + fb[0]; fi = pr + partner32(pr, kh); }
                { float pr = fa[1] + fb[1]; ff = pr + partner32(pr, kh); }
                { float pr = fa[2] + fb[2]; fg = pr + partner32(pr, kh); }
                { float pr = fa[3] + fb[3]; fo = pr + partner32(pr, kh); }
                float iv = sig2(fi);
                float fv = sig2(ff);
                float gv = fmaf(2.0f, sig2(fg), -1.0f);
                float ov = sig2(fo);
                c0 = fmaf(fv, c0, iv * gv);
                float hn = ov * tanh2(c0);
                if (kh == 0) h0s[p][j] = (half_t)hn;
            }
            __syncthreads();
        }
    } else {
        // ========= LAYER-1 (2 waves): lane = (unit j, matrix-half mh), one tick behind =========
        const int j  = ((wave & 1) << 5) | (lane & 31);   // hidden unit 0..63
        const int mh = lane >> 5;                          // 0: Wih1@h0, 1: Whh1@h1

        h2v wt[4][32];    // full rows of one matrix, 4 gates (128 VGPR)
        float bg[4];
        const float* WB = mh ? Whh1 : Wih1;
        #pragma unroll
        for (int s = 0; s < 4; ++s) {
            const int g = (s << 6) | j;
            const float sc = (s == 2) ? 2.0f * LOG2E : LOG2E;
            const volatile float* pw = WB + g * HH;
            #pragma unroll
            for (int r = 0; r < 32; ++r) {
                float w0 = pw[2*r], w1 = pw[2*r+1];
                wt[s][r] = h2v{(half_t)(w0 * sc), (half_t)(w1 * sc)};
            }
            bg[s] = (mh == 0) ? (bih1[g] + bhh1[g]) * sc : 0.0f;
        }

        float c1 = 0.0f;

        for (int tick = 0; tick <= TT; ++tick) {
            const int p = tick & 1;
            if (tick > 0) {
                const h8v* hp = mh ? (const h8v*)&h1s[p ^ 1][0]
                                   : (const h8v*)&h0s[p ^ 1][0];
                h8v H0 = hp[0], H1 = hp[1], H2 = hp[2], H3 = hp[3];
                h8v H4 = hp[4], H5 = hp[5], H6 = hp[6], H7 = hp[7];
                float fa[4], fb[4];
                #pragma unroll
                for (int s = 0; s < 4; ++s) {
                    float a = bg[s], bb = 0.0f;
                    DOT4(a,  &wt[s][0],  H0)
                    DOT4(a,  &wt[s][4],  H1)
                    DOT4(a,  &wt[s][8],  H2)
                    DOT4(a,  &wt[s][12], H3)
                    DOT4(bb, &wt[s][16], H4)
                    DOT4(bb, &wt[s][20], H5)
                    DOT4(bb, &wt[s][24], H6)
                    DOT4(bb, &wt[s][28], H7)
                    fa[s] = a; fb[s] = bb;
                }
                float fi, ff, fg, fo;
                { float pr = fa[0] + fb[0]; fi = pr + partner32(pr, mh); }
                { float pr = fa[1] + fb[1]; ff = pr + partner32(pr, mh); }
                { float pr = fa[2] + fb[2]; fg = pr + partner32(pr, mh); }
                { float pr = fa[3] + fb[3]; fo = pr + partner32(pr, mh); }
                float iv = sig2(fi);
                float fv = sig2(ff);
                float gv = fmaf(2.0f, sig2(fg), -1.0f);
                float ov = sig2(fo);
                c1 = fmaf(fv, c1, iv * gv);
                float hn = ov * tanh2(c1);
                if (mh == 0) h1s[p][j] = (half_t)hn;
            }
            __syncthreads();
        }
    }

    // h1(TT-1) was stored at tick TT into h1s[TT&1] = h1s[0]
    if (tid < 10) {
        float y = b1v[tid];
        #pragma unroll
        for (int k = 0; k < HH; ++k) y += W1[tid * HH + k] * (float)h1s[0][k];
        y = (y - rm[tid]) * rsqrtf(rv[tid] + 1e-5f) * gmma[tid] + beta[tid];
        y = fmaxf(y, 0.0f);
        yv[tid] = y * W2[tid];
    }
    __syncthreads();
    if (tid == 0) {
        float sacc = b2[0];
        #pragma unroll
        for (int k = 0; k < 10; ++k) sacc += yv[k];
        out[b] = sacc;
    }
}

extern "C" void kernel_launch(void* const* d_in, const int* in_sizes, int n_in,
                              void* d_out, int out_size, void* d_ws, size_t ws_size,
                              hipStream_t stream) {
    const float* x    = (const float*)d_in[0];
    const float* Wih0 = (const float*)d_in[1];
    const float* Whh0 = (const float*)d_in[2];
    const float* bih0 = (const float*)d_in[3];
    const float* bhh0 = (const float*)d_in[4];
    const float* Wih1 = (const float*)d_in[5];
    const float* Whh1 = (const float*)d_in[6];
    const float* bih1 = (const float*)d_in[7];
    const float* bhh1 = (const float*)d_in[8];
    const float* W1   = (const float*)d_in[9];
    const float* b1   = (const float*)d_in[10];
    const float* gmma = (const float*)d_in[11];
    const float* beta = (const float*)d_in[12];
    const float* rm   = (const float*)d_in[13];
    const float* rv   = (const float*)d_in[14];
    const float* W2   = (const float*)d_in[15];
    const float* b2   = (const float*)d_in[16];

    const int B = in_sizes[0] / (IND * TT);   // 256

    lstm2_fused<<<dim3(B), dim3(NT), 0, stream>>>(
        x, Wih0, Whh0, bih0, bhh0, Wih1, Whh1, bih1, bhh1,
        W1, b1, gmma, beta, rm, rv, W2, b2, (float*)d_out);
}

// Round 22
// 965.954 us; speedup vs baseline: 1.8603x; 1.0326x over previous
//
#include <hip/hip_runtime.h>
#include <math.h>

#define HH  64
#define TT  2048
#define IND 7
#define NT  256          // 4 waves: 2 L0 + 2 L1, one per SIMD

typedef _Float16 half_t;
typedef _Float16 h2v __attribute__((ext_vector_type(2)));
typedef _Float16 h8v __attribute__((ext_vector_type(8)));
typedef unsigned int u2v __attribute__((ext_vector_type(2)));

#define LOG2E 1.44269504088896f

// constant-index h2v slice of an h8v: exact VGPR subregister
#define S2C(V, I) __builtin_shufflevector(V, V, 2*(I), 2*(I)+1)

// f16 dot2 with fp32 accumulate
__device__ __forceinline__ float fdot2(h2v a, h2v b, float c) {
#if __has_builtin(__builtin_amdgcn_fdot2)
    return __builtin_amdgcn_fdot2(a, b, c, false);
#else
    return fmaf((float)a.x, (float)b.x, fmaf((float)a.y, (float)b.y, c));
#endif
}

__device__ __forceinline__ float exp2_fast(float x) {
#if __has_builtin(__builtin_amdgcn_exp2f)
    return __builtin_amdgcn_exp2f(x);
#else
    return exp2f(x);
#endif
}
__device__ __forceinline__ float rcp_fast(float x) {
#if __has_builtin(__builtin_amdgcn_rcpf)
    return __builtin_amdgcn_rcpf(x);
#else
    return __fdividef(1.0f, x);
#endif
}

// value held by the lane^32 partner (VALU pipe, v_permlane32_swap; verified r9-r21)
__device__ __forceinline__ float partner32(float x, int hi) {
#if __has_builtin(__builtin_amdgcn_permlane32_swap)
    u2v r = __builtin_amdgcn_permlane32_swap(__float_as_uint(x), __float_as_uint(x), false, false);
    return hi ? __uint_as_float(r.x) : __uint_as_float(r.y);
#else
    return __shfl_xor(x, 32);
#endif
}

// sigmoid with pre-scaled (log2e) argument (verified r13-r21)
__device__ __forceinline__ float sig2(float ahat) {
    return rcp_fast(1.0f + exp2_fast(-ahat));
}
__device__ __forceinline__ float tanh2(float c) {
    float e = exp2_fast(c * (-2.0f * LOG2E));
    return fmaf(2.0f, rcp_fast(1.0f + e), -1.0f);
}

// 4 f16-dot2 of weight block (W)[0..3] against the 4 h2v slices of h8v H
#define DOT4(ACC, W, H) \
    ACC = fdot2((W)[0], S2C(H, 0), ACC); \
    ACC = fdot2((W)[1], S2C(H, 1), ACC); \
    ACC = fdot2((W)[2], S2C(H, 2), ACC); \
    ACC = fdot2((W)[3], S2C(H, 3), ACC);

__global__ __launch_bounds__(NT) __attribute__((amdgpu_waves_per_eu(1, 1)))
void lstm2_fused(
    const float* __restrict__ x,     // (B,7,2048)
    const float* __restrict__ Wih0,  // (256,7)
    const float* __restrict__ Whh0,  // (256,64)
    const float* __restrict__ bih0, const float* __restrict__ bhh0,
    const float* __restrict__ Wih1,  // (256,64)
    const float* __restrict__ Whh1,  // (256,64)
    const float* __restrict__ bih1, const float* __restrict__ bhh1,
    const float* __restrict__ W1,    // (10,64)
    const float* __restrict__ b1v,   // (10)
    const float* __restrict__ gmma, const float* __restrict__ beta,
    const float* __restrict__ rm,   const float* __restrict__ rv,
    const float* __restrict__ W2,   // (1,10)
    const float* __restrict__ b2,   // (1)
    float* __restrict__ out)         // (B,1)
{
    const int b    = blockIdx.x;
    const int tid  = threadIdx.x;
    const int wave = tid >> 6;       // 0,1: L0   2,3: L1
    const int lane = tid & 63;

    __shared__ __align__(16) half_t xTh[TT][8];   // 32 KB, f16 x, [7]=0 pad
    __shared__ __align__(16) half_t h0s[2][HH];   // f16 hidden, double-buffered
    __shared__ __align__(16) half_t h1s[2][HH];
    __shared__ float yv[10];

    // ---- stage x[b] transposed, converted to f16 ----
    {
        const float* xg = x + (size_t)b * (IND * TT);
        for (int i = tid; i < IND * TT; i += NT) {
            int d = i >> 11;
            int t = i & (TT - 1);
            xTh[t][d] = (half_t)xg[i];
        }
        for (int t = tid; t < TT; t += NT) xTh[t][7] = (half_t)0.0f;
        if (tid < HH) {
            h0s[1][tid] = (half_t)0.0f;
            h1s[0][tid] = (half_t)0.0f;
            h1s[1][tid] = (half_t)0.0f;
        }
    }

    __syncthreads();

    if (wave < 2) {
        // ========= LAYER-0 (2 waves): lane = (unit j, k-half kh), 4 gates in-lane =========
        const int j  = ((wave & 1) << 5) | (lane & 31);   // hidden unit 0..63
        const int kh = lane >> 5;                          // k-half (lane bit 5)

        h2v wh[4][16];    // Whh0 half-rows, 4 gates
        h2v xw[4][4];     // Wih0 rows (kh=1 lanes only; zeros otherwise)
        float bg[4];
        #pragma unroll
        for (int s = 0; s < 4; ++s) {
            const int g = (s << 6) | j;
            const float sc = (s == 2) ? 2.0f * LOG2E : LOG2E;
            const float* pw = Whh0 + g * HH + 32 * kh;
            #pragma unroll
            for (int r = 0; r < 16; ++r)
                wh[s][r] = h2v{(half_t)(pw[2*r] * sc), (half_t)(pw[2*r+1] * sc)};
            float t8[8];
            #pragma unroll
            for (int d = 0; d < 8; ++d)
                t8[d] = (d < IND && kh) ? Wih0[g * IND + d] * sc : 0.0f;
            #pragma unroll
            for (int r = 0; r < 4; ++r)
                xw[s][r] = h2v{(half_t)t8[2*r], (half_t)t8[2*r+1]};
            bg[s] = (kh == 0) ? (bih0[g] + bhh0[g]) * sc : 0.0f;
        }

        float c0 = 0.0f;
        h8v XV = *((const h8v*)&xTh[0][0]);   // prefetched x(0); xTh is read-only

        for (int tick = 0; tick <= TT; ++tick) {
            const int p = tick & 1;
            if (tick < TT) {
                const h8v* hp = (const h8v*)&h0s[p ^ 1][32 * kh];
                h8v H0 = hp[0], H1 = hp[1], H2 = hp[2], H3 = hp[3];
                float fa[4], fb[4];
                #pragma unroll
                for (int s = 0; s < 4; ++s) {
                    float a = bg[s], bb = 0.0f;
                    DOT4(a,  &xw[s][0],  XV)          // x first (no LDS wait)
                    DOT4(a,  &wh[s][0],  H0)
                    DOT4(a,  &wh[s][4],  H1)
                    DOT4(bb, &wh[s][8],  H2)
                    DOT4(bb, &wh[s][12], H3)
                    fa[s] = a; fb[s] = bb;
                }
                float fi, ff, fg, fo;
                { float pr = fa[0] + fb[0]; fi = pr + partner32(pr, kh); }
                { float pr = fa[1] + fb[1]; ff = pr + partner32(pr, kh); }
                { float pr = fa[2] + fb[2]; fg = pr + partner32(pr, kh); }
                { float pr = fa[3] + fb[3]; fo = pr + partner32(pr, kh); }
                float iv = sig2(fi);
                float fv = sig2(ff);
                float gv = fmaf(2.0f, sig2(fg), -1.0f);
                float ov = sig2(fo);
                c0 = fmaf(fv, c0, iv * gv);
                float hn = ov * tanh2(c0);
                if (kh == 0) h0s[p][j] = (half_t)hn;
                // prefetch next x BEFORE the barrier (xTh never written again)
                XV = *((const h8v*)&xTh[(tick + 1) & (TT - 1)][0]);
            }
            __syncthreads();
        }
    } else {
        // ========= LAYER-1 (2 waves): lane = (unit j, matrix-half mh), one tick behind =========
        const int j  = ((wave & 1) << 5) | (lane & 31);   // hidden unit 0..63
        const int mh = lane >> 5;                          // 0: Wih1@h0, 1: Whh1@h1

        h2v wt[4][32];    // full rows of one matrix, 4 gates (128 VGPR)
        float bg[4];
        const float* WB = mh ? Whh1 : Wih1;
        #pragma unroll
        for (int s = 0; s < 4; ++s) {
            const int g = (s << 6) | j;
            const float sc = (s == 2) ? 2.0f * LOG2E : LOG2E;
            const float* pw = WB + g * HH;
            #pragma unroll
            for (int r = 0; r < 32; ++r)
                wt[s][r] = h2v{(half_t)(pw[2*r] * sc), (half_t)(pw[2*r+1] * sc)};
            bg[s] = (mh == 0) ? (bih1[g] + bhh1[g]) * sc : 0.0f;
        }

        float c1 = 0.0f;

        for (int tick = 0; tick <= TT; ++tick) {
            const int p = tick & 1;
            if (tick > 0) {
                const h8v* hp = mh ? (const h8v*)&h1s[p ^ 1][0]
                                   : (const h8v*)&h0s[p ^ 1][0];
                h8v H0 = hp[0], H1 = hp[1], H2 = hp[2], H3 = hp[3];
                h8v H4 = hp[4], H5 = hp[5], H6 = hp[6], H7 = hp[7];
                float fa[4], fb[4];
                #pragma unroll
                for (int s = 0; s < 4; ++s) {
                    float a = bg[s], bb = 0.0f;
                    DOT4(a,  &wt[s][0],  H0)
                    DOT4(a,  &wt[s][4],  H1)
                    DOT4(a,  &wt[s][8],  H2)
                    DOT4(a,  &wt[s][12], H3)
                    DOT4(bb, &wt[s][16], H4)
                    DOT4(bb, &wt[s][20], H5)
                    DOT4(bb, &wt[s][24], H6)
                    DOT4(bb, &wt[s][28], H7)
                    fa[s] = a; fb[s] = bb;
                }
                float fi, ff, fg, fo;
                { float pr = fa[0] + fb[0]; fi = pr + partner32(pr, mh); }
                { float pr = fa[1] + fb[1]; ff = pr + partner32(pr, mh); }
                { float pr = fa[2] + fb[2]; fg = pr + partner32(pr, mh); }
                { float pr = fa[3] + fb[3]; fo = pr + partner32(pr, mh); }
                float iv = sig2(fi);
                float fv = sig2(ff);
                float gv = fmaf(2.0f, sig2(fg), -1.0f);
                float ov = sig2(fo);
                c1 = fmaf(fv, c1, iv * gv);
                float hn = ov * tanh2(c1);
                if (mh == 0) h1s[p][j] = (half_t)hn;
            }
            __syncthreads();
        }
    }

    // h1(TT-1) was stored at tick TT into h1s[TT&1] = h1s[0]
    if (tid < 10) {
        float y = b1v[tid];
        #pragma unroll
        for (int k = 0; k < HH; ++k) y += W1[tid * HH + k] * (float)h1s[0][k];
        y = (y - rm[tid]) * rsqrtf(rv[tid] + 1e-5f) * gmma[tid] + beta[tid];
        y = fmaxf(y, 0.0f);
        yv[tid] = y * W2[tid];
    }
    __syncthreads();
    if (tid == 0) {
        float sacc = b2[0];
        #pragma unroll
        for (int k = 0; k < 10; ++k) sacc += yv[k];
        out[b] = sacc;
    }
}

extern "C" void kernel_launch(void* const* d_in, const int* in_sizes, int n_in,
                              void* d_out, int out_size, void* d_ws, size_t ws_size,
                              hipStream_t stream) {
    const float* x    = (const float*)d_in[0];
    const float* Wih0 = (const float*)d_in[1];
    const float* Whh0 = (const float*)d_in[2];
    const float* bih0 = (const float*)d_in[3];
    const float* bhh0 = (const float*)d_in[4];
    const float* Wih1 = (const float*)d_in[5];
    const float* Whh1 = (const float*)d_in[6];
    const float* bih1 = (const float*)d_in[7];
    const float* bhh1 = (const float*)d_in[8];
    const float* W1   = (const float*)d_in[9];
    const float* b1   = (const float*)d_in[10];
    const float* gmma = (const float*)d_in[11];
    const float* beta = (const float*)d_in[12];
    const float* rm   = (const float*)d_in[13];
    const float* rv   = (const float*)d_in[14];
    const float* W2   = (const float*)d_in[15];
    const float* b2   = (const float*)d_in[16];

    const int B = in_sizes[0] / (IND * TT);   // 256

    lstm2_fused<<<dim3(B), dim3(NT), 0, stream>>>(
        x, Wih0, Whh0, bih0, bhh0, Wih1, Whh1, bih1, bhh1,
        W1, b1, gmma, beta, rm, rv, W2, b2, (float*)d_out);
}